// Round 5
// baseline (598.515 us; speedup 1.0000x reference)
//
#include <hip/hip_runtime.h>
#include <cstdint>
#include <cstddef>

typedef unsigned short u16x8 __attribute__((ext_vector_type(8)));
typedef unsigned short u16x4 __attribute__((ext_vector_type(4)));
typedef __bf16 bf16x8 __attribute__((ext_vector_type(8)));
typedef float f32x4 __attribute__((ext_vector_type(4)));

__device__ __forceinline__ float b2f(unsigned short u) {
    union { unsigned int i; float f; } v;
    v.i = ((unsigned int)u) << 16;
    return v.f;
}

__device__ __forceinline__ unsigned short f2b(float f) {
    union { float f; unsigned int i; } v;
    v.f = f;
    unsigned int x = v.i;
    unsigned int lsb = (x >> 16) & 1u;
    x += 0x7FFFu + lsb;           // round-to-nearest-even
    return (unsigned short)(x >> 16);
}

__device__ __forceinline__ float gelu_exact(float x) {
    return 0.5f * x * (1.0f + erff(x * 0.70710678118654752f));
}

// async 16B global -> LDS (DMA). LDS base wave-uniform; lane i -> base+16i.
__device__ __forceinline__ void ld_lds16(const unsigned short* g, unsigned short* l) {
    __builtin_amdgcn_global_load_lds(
        (const __attribute__((address_space(1))) void*)g,
        (__attribute__((address_space(3))) void*)l, 16, 0, 0);
}

// ---------------------------------------------------------------------------
// Transpose + cast (+ optional per-input-row scale): in R x C fp32 row-major,
// out C x R bf16 row-major. out[c,r] = scale[r]*in[r,c].
// ---------------------------------------------------------------------------
__global__ void transpose_f32_bf16(const float* __restrict__ in,
                                   unsigned short* __restrict__ out, int R, int C,
                                   const float* __restrict__ scale) {
    __shared__ float tile[32][33];
    int x = blockIdx.x * 32 + threadIdx.x;
    int y0 = blockIdx.y * 32;
    for (int k = 0; k < 32; k += 8) {
        float v = in[(size_t)(y0 + threadIdx.y + k) * C + x];
        if (scale) v *= scale[y0 + threadIdx.y + k];
        tile[threadIdx.y + k][threadIdx.x] = v;
    }
    __syncthreads();
    int ox = y0 + threadIdx.x;
    int oy = blockIdx.x * 32;
    for (int k = 0; k < 32; k += 8)
        out[(size_t)(oy + threadIdx.y + k) * R + ox] = f2b(tile[threadIdx.x][threadIdx.y + k]);
}

// zero S/cv and the two counters (ws is poisoned before every call)
__global__ void init_misc(float* __restrict__ S, float* __restrict__ cv,
                          int* __restrict__ cnt) {
    int t = blockIdx.x * 256 + threadIdx.x;
    if (t < 1024) { S[t] = 0.f; cv[t] = 0.f; }
    if (t < 2) cnt[t] = 0;
}

// S[c] = sum_f g[f]*W2[f,c];  cv[c] = sum_f b[f]*W2[f,c]   (W2 is F x H fp32)
__global__ void colreduce_w2(const float* __restrict__ W2, const float* __restrict__ g,
                             const float* __restrict__ b, float* __restrict__ S,
                             float* __restrict__ cv) {
    int c = blockIdx.x * 256 + threadIdx.x;     // gridDim.x = 4  -> 1024 cols
    int f0 = blockIdx.y * 256;                  // gridDim.y = 16 -> 4096 rows
    float s = 0.f, cc = 0.f;
    for (int f = f0; f < f0 + 256; ++f) {
        float w = W2[(size_t)f * 1024 + c];
        s = fmaf(g[f], w, s);
        cc = fmaf(b[f], w, cc);
    }
    atomicAdd(&S[c], s);
    atomicAdd(&cv[c], cc);
}

// Build compacted row lists per adapter. Order is arbitrary (atomics) but the
// result is permutation-invariant downstream.
__global__ void build_lists(const int* __restrict__ widx, int* __restrict__ cnt,
                            int* __restrict__ rl0, int* __restrict__ rl1) {
    int i = blockIdx.x * 256 + threadIdx.x;     // grid 32 -> 8192
    int id = widx[i];
    if (id == 0)      rl0[atomicAdd(&cnt[0], 1)] = i;
    else if (id == 1) rl1[atomicAdd(&cnt[1], 1)] = i;
}

// ---------------------------------------------------------------------------
// LayerNorm of x (fp32, 1024 cols) -> bf16, vectorized float4.
// ---------------------------------------------------------------------------
__global__ __launch_bounds__(256) void ln1024(const float* __restrict__ x,
                                              unsigned short* __restrict__ xn,
                                              const float* __restrict__ g,
                                              const float* __restrict__ b) {
    const int row = blockIdx.x, t = threadIdx.x;
    const float4 v = ((const float4*)(x + (size_t)row * 1024))[t];
    float s = v.x + v.y + v.z + v.w;
    float s2 = v.x * v.x + v.y * v.y + v.z * v.z + v.w * v.w;
#pragma unroll
    for (int o = 32; o > 0; o >>= 1) {
        s  += __shfl_down(s, o, 64);
        s2 += __shfl_down(s2, o, 64);
    }
    __shared__ float red[8];
    int lane = t & 63, w = t >> 6;
    if (lane == 0) { red[w] = s; red[4 + w] = s2; }
    __syncthreads();
    if (t == 0) {
        red[0] = red[0] + red[1] + red[2] + red[3];
        red[4] = red[4] + red[5] + red[6] + red[7];
    }
    __syncthreads();
    float mu = red[0] * (1.0f / 1024.0f);
    float var = red[4] * (1.0f / 1024.0f) - mu * mu;
    float rs = rsqrtf(var + 1e-5f);
    float4 gg = ((const float4*)g)[t];
    float4 bb = ((const float4*)b)[t];
    u16x4 o;
    o[0] = f2b((v.x - mu) * rs * gg.x + bb.x);
    o[1] = f2b((v.y - mu) * rs * gg.y + bb.y);
    o[2] = f2b((v.z - mu) * rs * gg.z + bb.z);
    o[3] = f2b((v.w - mu) * rs * gg.w + bb.w);
    ((u16x4*)(xn + (size_t)row * 1024))[t] = o;
}

// Per-row mean / rsqrt(var) of h (bf16, 4096 cols), vectorized u16x8.
__global__ __launch_bounds__(256) void row_stats(const unsigned short* __restrict__ h,
                                                 float* __restrict__ mu,
                                                 float* __restrict__ rs) {
    const int row = blockIdx.x, t = threadIdx.x;
    const u16x8* hv = (const u16x8*)(h + (size_t)row * 4096);
    float s = 0.f, s2 = 0.f;
#pragma unroll
    for (int i = 0; i < 2; ++i) {
        u16x8 v = hv[t + i * 256];
#pragma unroll
        for (int e = 0; e < 8; ++e) { float f = b2f(v[e]); s += f; s2 += f * f; }
    }
#pragma unroll
    for (int o = 32; o > 0; o >>= 1) {
        s  += __shfl_down(s, o, 64);
        s2 += __shfl_down(s2, o, 64);
    }
    __shared__ float red[8];
    int lane = t & 63, w = t >> 6;
    if (lane == 0) { red[w] = s; red[4 + w] = s2; }
    __syncthreads();
    if (t == 0) {
        float S  = red[0] + red[1] + red[2] + red[3];
        float S2 = red[4] + red[5] + red[6] + red[7];
        float m = S * (1.0f / 4096.0f);
        float var = S2 * (1.0f / 4096.0f) - m * m;
        mu[row] = m;
        rs[row] = rsqrtf(var + 1e-5f);
    }
}

// ---------------------------------------------------------------------------
// GEMM: A[M x K] * BT[N x K]^T (+ epilogue). A,BT bf16; fp32 acc.
// Tile 128x128x32; 256 threads = 4 waves, each 64x64. Double-buffered LDS,
// one barrier per K-iter (DMA k+1 in flight across compute k).
// EPI 0: direct A; store bf16 gelu(val+bias)               (base FFN up)
// EPI 1: INDIRECT A rows via rlist (compacted gather), early-exit on *cnt;
//        store bf16 gelu(val+bias) to compacted Cb          (adapter ups)
// EPI 2: direct A (compacted tc), early-exit on *cnt; scatter-store
//        bf16 (val+bias) to Cb[rlist[row]]                  (adapter downs)
// EPI 3: LN-fold + adaptive combine, fp32 out:
//        v = rs[row]*acc - rs[row]*mu[row]*S[col] + cv[col] + bias[col]
//        out = v*wm + (idx<=1 ? adp : xn)*(1-wm)            (final GEMM)
// ---------------------------------------------------------------------------
template <int EPI>
__global__ __launch_bounds__(256) void gemm_bt(
    const unsigned short* __restrict__ A, int lda,
    const unsigned short* __restrict__ BT, int ldb,
    const float* __restrict__ bias,
    unsigned short* __restrict__ Cb, float* __restrict__ Cf, int N, int K,
    const int* __restrict__ rlist, const int* __restrict__ cnt,
    const int* __restrict__ idx, const float* __restrict__ wm,
    const unsigned short* __restrict__ adp, const unsigned short* __restrict__ xn,
    const float* __restrict__ mu, const float* __restrict__ rs,
    const float* __restrict__ Svec, const float* __restrict__ cvec) {
    __shared__ __align__(16) unsigned short As[2][128 * 32];
    __shared__ __align__(16) unsigned short Bs[2][128 * 32];

    const int m0 = blockIdx.y * 128;
    const int n0 = blockIdx.x * 128;

    int cnt_ = 0;
    if (EPI == 1 || EPI == 2) {
        cnt_ = *cnt;
        if (m0 >= cnt_) return;          // wave-uniform early exit, before any LDS
    }

    const int t = threadIdx.x;
    const int lane = t & 63;
    const int wid = t >> 6;

    // staging: lane i covers LDS rel-row i/4, chunk i%4 (XOR row-swizzled src)
    const int srow = lane >> 2;
    const int sch  = (lane & 3) ^ (srow & 3);
    const int scol = sch << 3;

    const int wr = (wid >> 1) << 6;
    const int wc = (wid & 1) << 6;
    const int ml = lane & 15;
    const int q = lane >> 4;
    const int qsw = ((q ^ (ml & 3)) << 3);

    // K-invariant global row pointers (indirect gather for EPI 1)
    const unsigned short* aptr[2];
    const unsigned short* bptr[2];
#pragma unroll
    for (int hh = 0; hh < 2; ++hh) {
        int grow = m0 + wid * 32 + hh * 16 + srow;
        int arow;
        if (EPI == 1) arow = (grow < cnt_) ? rlist[grow] : 0;
        else          arow = grow;
        aptr[hh] = A  + (size_t)arow * lda + scol;
        bptr[hh] = BT + (size_t)(n0 + wid * 32 + hh * 16 + srow) * ldb + scol;
    }

    f32x4 acc[4][4];
#pragma unroll
    for (int i = 0; i < 4; ++i)
#pragma unroll
        for (int j = 0; j < 4; ++j)
#pragma unroll
            for (int r = 0; r < 4; ++r) acc[i][j][r] = 0.0f;

    const int nk = K >> 5;

#define STAGE(KT, BUF)                                                          \
    {                                                                           \
        _Pragma("unroll")                                                       \
        for (int hh = 0; hh < 2; ++hh) {                                        \
            int rbase = wid * 32 + hh * 16;                                     \
            ld_lds16(aptr[hh] + (KT) * 32, &As[BUF][rbase * 32]);               \
            ld_lds16(bptr[hh] + (KT) * 32, &Bs[BUF][rbase * 32]);               \
        }                                                                       \
    }

    STAGE(0, 0);
    for (int kt = 0; kt < nk; ++kt) {
        const int cur = kt & 1;
        __syncthreads();                 // drains DMA(kt), in flight since kt-1
        if (kt + 1 < nk) STAGE(kt + 1, cur ^ 1);

        bf16x8 af[4], bf[4];
#pragma unroll
        for (int i = 0; i < 4; ++i)
            af[i] = *(const bf16x8*)(&As[cur][(wr + i * 16 + ml) * 32 + qsw]);
#pragma unroll
        for (int j = 0; j < 4; ++j)
            bf[j] = *(const bf16x8*)(&Bs[cur][(wc + j * 16 + ml) * 32 + qsw]);
#pragma unroll
        for (int i = 0; i < 4; ++i)
#pragma unroll
            for (int j = 0; j < 4; ++j)
                acc[i][j] = __builtin_amdgcn_mfma_f32_16x16x32_bf16(af[i], bf[j], acc[i][j], 0, 0, 0);
    }
#undef STAGE

    // C/D layout: col = lane&15, row = quad*4 + reg  [m89/m91-verified]
#pragma unroll
    for (int i = 0; i < 4; ++i) {
#pragma unroll
        for (int j = 0; j < 4; ++j) {
            int col = n0 + wc + j * 16 + ml;
            float bv = bias[col];
            float sv = 0.f, cvv = 0.f;
            if (EPI == 3) { sv = Svec[col]; cvv = cvec[col]; }
#pragma unroll
            for (int r = 0; r < 4; ++r) {
                int row = m0 + wr + i * 16 + q * 4 + r;
                size_t off = (size_t)row * N + col;
                if (EPI == 0 || EPI == 1) {
                    Cb[off] = f2b(gelu_exact(acc[i][j][r] + bv));
                } else if (EPI == 2) {
                    if (row < cnt_)
                        Cb[(size_t)rlist[row] * N + col] = f2b(acc[i][j][r] + bv);
                } else {
                    float rr = rs[row];
                    float v2 = rr * acc[i][j][r] - rr * mu[row] * sv + cvv + bv;
                    float w = wm[row];
                    int id = idx[row];
                    float a = b2f((id <= 1) ? adp[off] : xn[off]);
                    Cf[off] = v2 * w + a * (1.0f - w);
                }
            }
        }
    }
}

// ---------------------------------------------------------------------------
extern "C" void kernel_launch(void* const* d_in, const int* in_sizes, int n_in,
                              void* d_out, int out_size, void* d_ws, size_t ws_size,
                              hipStream_t stream) {
    const float* x       = (const float*)d_in[0];
    const float* wm      = (const float*)d_in[1];
    const int*   widx    = (const int*)d_in[2];
    const float* ln_in_g = (const float*)d_in[3];
    const float* ln_in_b = (const float*)d_in[4];
    const float* W1      = (const float*)d_in[5];
    const float* b1      = (const float*)d_in[6];
    const float* ln_h_g  = (const float*)d_in[7];
    const float* ln_h_b  = (const float*)d_in[8];
    const float* W2      = (const float*)d_in[9];
    const float* b2      = (const float*)d_in[10];
    const float* a256_w1 = (const float*)d_in[11];
    const float* a256_b1 = (const float*)d_in[12];
    const float* a256_w2 = (const float*)d_in[13];
    const float* a256_b2 = (const float*)d_in[14];
    const float* a512_w1 = (const float*)d_in[15];
    const float* a512_b1 = (const float*)d_in[16];
    const float* a512_w2 = (const float*)d_in[17];
    const float* a512_b2 = (const float*)d_in[18];
    float* out = (float*)d_out;

    const int T = 8192, H = 1024, F = 4096;

    unsigned short* ws0   = (unsigned short*)d_ws;
    unsigned short* xn    = ws0;                          // T*H          bf16
    unsigned short* h     = xn    + (size_t)T * H;        // T*F          bf16
    unsigned short* tc0   = h     + (size_t)T * F;        // (T+128)*256  bf16
    unsigned short* tc1   = tc0   + (size_t)(T + 128) * 256; // (T+128)*512
    unsigned short* adp   = tc1   + (size_t)(T + 128) * 512; // T*H
    unsigned short* W1T   = adp   + (size_t)T * H;        // F*H
    unsigned short* W2T   = W1T   + (size_t)H * F;        // H*F  (g-scaled)
    unsigned short* aw1T0 = W2T   + (size_t)F * H;        // 256*H
    unsigned short* aw1T1 = aw1T0 + (size_t)256 * H;      // 512*H
    unsigned short* aw2T0 = aw1T1 + (size_t)512 * H;      // H*256
    unsigned short* aw2T1 = aw2T0 + (size_t)H * 256;      // H*512
    float* fbase = (float*)(aw2T1 + (size_t)H * 512);
    float* Svec  = fbase;             // 1024
    float* cvec  = Svec + 1024;       // 1024
    float* muv   = cvec + 1024;       // 8192
    float* rsv   = muv + 8192;        // 8192
    int*   cnts  = (int*)(rsv + 8192);// 2
    int*   rl0   = cnts + 2;          // 8192
    int*   rl1   = rl0 + 8192;        // 8192

    dim3 tb(32, 8);
    transpose_f32_bf16<<<dim3(F / 32,   H / 32), tb, 0, stream>>>(W1, W1T, H, F, nullptr);
    transpose_f32_bf16<<<dim3(H / 32,   F / 32), tb, 0, stream>>>(W2, W2T, F, H, ln_h_g);
    transpose_f32_bf16<<<dim3(256 / 32, H / 32), tb, 0, stream>>>(a256_w1, aw1T0, H, 256, nullptr);
    transpose_f32_bf16<<<dim3(512 / 32, H / 32), tb, 0, stream>>>(a512_w1, aw1T1, H, 512, nullptr);
    transpose_f32_bf16<<<dim3(H / 32, 256 / 32), tb, 0, stream>>>(a256_w2, aw2T0, 256, H, nullptr);
    transpose_f32_bf16<<<dim3(H / 32, 512 / 32), tb, 0, stream>>>(a512_w2, aw2T1, 512, H, nullptr);

    init_misc<<<4, 256, 0, stream>>>(Svec, cvec, cnts);
    colreduce_w2<<<dim3(4, 16), 256, 0, stream>>>(W2, ln_h_g, ln_h_b, Svec, cvec);
    build_lists<<<32, 256, 0, stream>>>(widx, cnts, rl0, rl1);

    // x (fp32) -> x_norm (bf16)
    ln1024<<<T, 256, 0, stream>>>(x, xn, ln_in_g, ln_in_b);

    // compacted adapter ups: tc = gelu(xn[rl] @ a_w1 + b)
    gemm_bt<1><<<dim3(2, 64), 256, 0, stream>>>(
        xn, H, aw1T0, H, a256_b1, tc0, nullptr, 256, H,
        rl0, cnts + 0, nullptr, nullptr, nullptr, nullptr, nullptr, nullptr, nullptr, nullptr);
    gemm_bt<1><<<dim3(4, 64), 256, 0, stream>>>(
        xn, H, aw1T1, H, a512_b1, tc1, nullptr, 512, H,
        rl1, cnts + 1, nullptr, nullptr, nullptr, nullptr, nullptr, nullptr, nullptr, nullptr);

    // compacted adapter downs: adp[rl[r]] = tc @ a_w2 + b
    gemm_bt<2><<<dim3(8, 64), 256, 0, stream>>>(
        tc0, 256, aw2T0, 256, a256_b2, adp, nullptr, H, 256,
        rl0, cnts + 0, nullptr, nullptr, nullptr, nullptr, nullptr, nullptr, nullptr, nullptr);
    gemm_bt<2><<<dim3(8, 64), 256, 0, stream>>>(
        tc1, 512, aw2T1, 512, a512_b2, adp, nullptr, H, 512,
        rl1, cnts + 1, nullptr, nullptr, nullptr, nullptr, nullptr, nullptr, nullptr, nullptr);

    // base FFN up: h = gelu(xn @ W1 + b1)
    gemm_bt<0><<<dim3(F / 128, T / 128), 256, 0, stream>>>(
        xn, H, W1T, H, b1, h, nullptr, F, H,
        nullptr, nullptr, nullptr, nullptr, nullptr, nullptr, nullptr, nullptr, nullptr, nullptr);

    // LN-h stats (LN itself folded into the final GEMM)
    row_stats<<<T, 256, 0, stream>>>(h, muv, rsv);

    // out = (LN(h) @ W2 + b2)*wm + adaptive*(1-wm), LN folded:
    gemm_bt<3><<<dim3(H / 128, T / 128), 256, 0, stream>>>(
        h, F, W2T, F, b2, nullptr, out, H, F,
        nullptr, nullptr, widx, wm, adp, xn, muv, rsv, Svec, cvec);
}

// Round 6
// 523.418 us; speedup vs baseline: 1.1435x; 1.1435x over previous
//
#include <hip/hip_runtime.h>
#include <cstdint>
#include <cstddef>

typedef unsigned short u16x8 __attribute__((ext_vector_type(8)));
typedef unsigned short u16x4 __attribute__((ext_vector_type(4)));
typedef __bf16 bf16x8 __attribute__((ext_vector_type(8)));
typedef float f32x4 __attribute__((ext_vector_type(4)));

__device__ __forceinline__ float b2f(unsigned short u) {
    union { unsigned int i; float f; } v;
    v.i = ((unsigned int)u) << 16;
    return v.f;
}

__device__ __forceinline__ unsigned short f2b(float f) {
    union { float f; unsigned int i; } v;
    v.f = f;
    unsigned int x = v.i;
    unsigned int lsb = (x >> 16) & 1u;
    x += 0x7FFFu + lsb;           // round-to-nearest-even
    return (unsigned short)(x >> 16);
}

__device__ __forceinline__ float gelu_exact(float x) {
    return 0.5f * x * (1.0f + erff(x * 0.70710678118654752f));
}

// async 16B global -> LDS (DMA). LDS base wave-uniform; lane i -> base+16i.
__device__ __forceinline__ void ld_lds16(const unsigned short* g, unsigned short* l) {
    __builtin_amdgcn_global_load_lds(
        (const __attribute__((address_space(1))) void*)g,
        (__attribute__((address_space(3))) void*)l, 16, 0, 0);
}

// ---------------------------------------------------------------------------
// Transpose + cast (+ optional per-input-row scale): in R x C fp32 row-major,
// out C x R bf16 row-major. out[c,r] = scale[r]*in[r,c].
// ---------------------------------------------------------------------------
__global__ void transpose_f32_bf16(const float* __restrict__ in,
                                   unsigned short* __restrict__ out, int R, int C,
                                   const float* __restrict__ scale) {
    __shared__ float tile[32][33];
    int x = blockIdx.x * 32 + threadIdx.x;
    int y0 = blockIdx.y * 32;
    for (int k = 0; k < 32; k += 8) {
        float v = in[(size_t)(y0 + threadIdx.y + k) * C + x];
        if (scale) v *= scale[y0 + threadIdx.y + k];
        tile[threadIdx.y + k][threadIdx.x] = v;
    }
    __syncthreads();
    int ox = y0 + threadIdx.x;
    int oy = blockIdx.x * 32;
    for (int k = 0; k < 32; k += 8)
        out[(size_t)(oy + threadIdx.y + k) * R + ox] = f2b(tile[threadIdx.x][threadIdx.y + k]);
}

// zero S/cv and the two counters (ws is poisoned before every call)
__global__ void init_misc(float* __restrict__ S, float* __restrict__ cv,
                          int* __restrict__ cnt) {
    int t = blockIdx.x * 256 + threadIdx.x;
    if (t < 1024) { S[t] = 0.f; cv[t] = 0.f; }
    if (t < 2) cnt[t] = 0;
}

// S[c] = sum_f g[f]*W2[f,c];  cv[c] = sum_f b[f]*W2[f,c]   (W2 is F x H fp32)
__global__ void colreduce_w2(const float* __restrict__ W2, const float* __restrict__ g,
                             const float* __restrict__ b, float* __restrict__ S,
                             float* __restrict__ cv) {
    int c = blockIdx.x * 256 + threadIdx.x;     // gridDim.x = 4  -> 1024 cols
    int f0 = blockIdx.y * 256;                  // gridDim.y = 16 -> 4096 rows
    float s = 0.f, cc = 0.f;
    for (int f = f0; f < f0 + 256; ++f) {
        float w = W2[(size_t)f * 1024 + c];
        s = fmaf(g[f], w, s);
        cc = fmaf(b[f], w, cc);
    }
    atomicAdd(&S[c], s);
    atomicAdd(&cv[c], cc);
}

// Build compacted row lists per adapter (order arbitrary; downstream is
// permutation-invariant).
__global__ void build_lists(const int* __restrict__ widx, int* __restrict__ cnt,
                            int* __restrict__ rl0, int* __restrict__ rl1) {
    int i = blockIdx.x * 256 + threadIdx.x;     // grid 32 -> 8192
    int id = widx[i];
    if (id == 0)      rl0[atomicAdd(&cnt[0], 1)] = i;
    else if (id == 1) rl1[atomicAdd(&cnt[1], 1)] = i;
}

// xc[r,:] = xn[rl[r],:] for r < cnt  (blockIdx.y selects list)
__global__ __launch_bounds__(256) void gather_rows(
    const unsigned short* __restrict__ xn,
    const int* __restrict__ rl0, const int* __restrict__ rl1,
    const int* __restrict__ cnt,
    unsigned short* __restrict__ xc0, unsigned short* __restrict__ xc1) {
    const int list = blockIdx.y;
    const int r = blockIdx.x;
    if (r >= cnt[list]) return;
    const int src = list ? rl1[r] : rl0[r];
    unsigned short* dst = list ? xc1 : xc0;
    ((u16x4*)(dst + (size_t)r * 1024))[threadIdx.x] =
        ((const u16x4*)(xn + (size_t)src * 1024))[threadIdx.x];
}

// ---------------------------------------------------------------------------
// LayerNorm of x (fp32, 1024 cols) -> bf16, vectorized float4.
// ---------------------------------------------------------------------------
__global__ __launch_bounds__(256) void ln1024(const float* __restrict__ x,
                                              unsigned short* __restrict__ xn,
                                              const float* __restrict__ g,
                                              const float* __restrict__ b) {
    const int row = blockIdx.x, t = threadIdx.x;
    const float4 v = ((const float4*)(x + (size_t)row * 1024))[t];
    float s = v.x + v.y + v.z + v.w;
    float s2 = v.x * v.x + v.y * v.y + v.z * v.z + v.w * v.w;
#pragma unroll
    for (int o = 32; o > 0; o >>= 1) {
        s  += __shfl_down(s, o, 64);
        s2 += __shfl_down(s2, o, 64);
    }
    __shared__ float red[8];
    int lane = t & 63, w = t >> 6;
    if (lane == 0) { red[w] = s; red[4 + w] = s2; }
    __syncthreads();
    if (t == 0) {
        red[0] = red[0] + red[1] + red[2] + red[3];
        red[4] = red[4] + red[5] + red[6] + red[7];
    }
    __syncthreads();
    float mu = red[0] * (1.0f / 1024.0f);
    float var = red[4] * (1.0f / 1024.0f) - mu * mu;
    float rs = rsqrtf(var + 1e-5f);
    float4 gg = ((const float4*)g)[t];
    float4 bb = ((const float4*)b)[t];
    u16x4 o;
    o[0] = f2b((v.x - mu) * rs * gg.x + bb.x);
    o[1] = f2b((v.y - mu) * rs * gg.y + bb.y);
    o[2] = f2b((v.z - mu) * rs * gg.z + bb.z);
    o[3] = f2b((v.w - mu) * rs * gg.w + bb.w);
    ((u16x4*)(xn + (size_t)row * 1024))[t] = o;
}

// Per-row mean / rsqrt(var) of h (bf16, 4096 cols), vectorized u16x8.
__global__ __launch_bounds__(256) void row_stats(const unsigned short* __restrict__ h,
                                                 float* __restrict__ mu,
                                                 float* __restrict__ rs) {
    const int row = blockIdx.x, t = threadIdx.x;
    const u16x8* hv = (const u16x8*)(h + (size_t)row * 4096);
    float s = 0.f, s2 = 0.f;
#pragma unroll
    for (int i = 0; i < 2; ++i) {
        u16x8 v = hv[t + i * 256];
#pragma unroll
        for (int e = 0; e < 8; ++e) { float f = b2f(v[e]); s += f; s2 += f * f; }
    }
#pragma unroll
    for (int o = 32; o > 0; o >>= 1) {
        s  += __shfl_down(s, o, 64);
        s2 += __shfl_down(s2, o, 64);
    }
    __shared__ float red[8];
    int lane = t & 63, w = t >> 6;
    if (lane == 0) { red[w] = s; red[4 + w] = s2; }
    __syncthreads();
    if (t == 0) {
        float S  = red[0] + red[1] + red[2] + red[3];
        float S2 = red[4] + red[5] + red[6] + red[7];
        float m = S * (1.0f / 4096.0f);
        float var = S2 * (1.0f / 4096.0f) - m * m;
        mu[row] = m;
        rs[row] = rsqrtf(var + 1e-5f);
    }
}

// ---------------------------------------------------------------------------
// GEMM: A[M x K] * BT[N x K]^T (+ epilogue). A,BT bf16; fp32 acc.
// Tile 128x128x32; 256 threads = 4 waves, each 64x64. Double-buffered LDS,
// one barrier per K-iter (DMA k+1 in flight across compute k). Inline
// staging addresses (round-4 structure: VGPR<=128 with launch_bounds(256,4)).
// GATED: wave-uniform early exit when the M-block is beyond *cnt.
// EPI 0: store bf16 gelu(val+bias)                      (ups; A may be compact)
// EPI 2: scatter bf16 (val+bias) -> Cb[rlist[row]]       (adapter downs)
// EPI 3: LN-fold + adaptive combine, fp32 out            (final GEMM)
// ---------------------------------------------------------------------------
template <int EPI, bool GATED>
__global__ __launch_bounds__(256, 4) void gemm_bt(
    const unsigned short* __restrict__ A, int lda,
    const unsigned short* __restrict__ BT, int ldb,
    const float* __restrict__ bias,
    unsigned short* __restrict__ Cb, float* __restrict__ Cf, int N, int K,
    const int* __restrict__ rlist, const int* __restrict__ cnt,
    const int* __restrict__ idx, const float* __restrict__ wm,
    const unsigned short* __restrict__ adp, const unsigned short* __restrict__ xn,
    const float* __restrict__ mu, const float* __restrict__ rs,
    const float* __restrict__ Svec, const float* __restrict__ cvec) {
    __shared__ __align__(16) unsigned short As[2][128 * 32];
    __shared__ __align__(16) unsigned short Bs[2][128 * 32];

    const int m0 = blockIdx.y * 128;
    const int n0 = blockIdx.x * 128;

    int cnt_ = 0;
    if (GATED) {
        cnt_ = *cnt;
        if (m0 >= cnt_) return;          // wave-uniform early exit
    }

    const int t = threadIdx.x;
    const int lane = t & 63;
    const int wid = t >> 6;

    // staging: lane i covers LDS rel-row i/4, chunk i%4 (XOR row-swizzled src)
    const int srow = lane >> 2;
    const int scol = ((lane & 3) ^ (srow & 3)) << 3;

    const int wr = (wid >> 1) << 6;
    const int wc = (wid & 1) << 6;
    const int ml = lane & 15;
    const int q = lane >> 4;
    const int qsw = ((q ^ (ml & 3)) << 3);

    f32x4 acc[4][4];
#pragma unroll
    for (int i = 0; i < 4; ++i)
#pragma unroll
        for (int j = 0; j < 4; ++j)
#pragma unroll
            for (int r = 0; r < 4; ++r) acc[i][j][r] = 0.0f;

    const int nk = K >> 5;

#define STAGE(KT, BUF)                                                          \
    {                                                                           \
        _Pragma("unroll")                                                       \
        for (int hh = 0; hh < 2; ++hh) {                                        \
            int rbase = wid * 32 + hh * 16;                                     \
            int row = rbase + srow;                                             \
            ld_lds16(A  + (size_t)(m0 + row) * lda + (KT) * 32 + scol,          \
                     &As[BUF][rbase * 32]);                                     \
            ld_lds16(BT + (size_t)(n0 + row) * ldb + (KT) * 32 + scol,          \
                     &Bs[BUF][rbase * 32]);                                     \
        }                                                                       \
    }

    STAGE(0, 0);
    for (int kt = 0; kt < nk; ++kt) {
        const int cur = kt & 1;
        __syncthreads();                 // drains DMA(kt), in flight since kt-1
        if (kt + 1 < nk) STAGE(kt + 1, cur ^ 1);

        bf16x8 af[4], bf[4];
#pragma unroll
        for (int i = 0; i < 4; ++i)
            af[i] = *(const bf16x8*)(&As[cur][(wr + i * 16 + ml) * 32 + qsw]);
#pragma unroll
        for (int j = 0; j < 4; ++j)
            bf[j] = *(const bf16x8*)(&Bs[cur][(wc + j * 16 + ml) * 32 + qsw]);
#pragma unroll
        for (int i = 0; i < 4; ++i)
#pragma unroll
            for (int j = 0; j < 4; ++j)
                acc[i][j] = __builtin_amdgcn_mfma_f32_16x16x32_bf16(af[i], bf[j], acc[i][j], 0, 0, 0);
    }
#undef STAGE

    // Epilogue. C/D layout: col = lane&15, row = quad*4 + reg [m89/m91].
    // Col-scalars hoisted (independent of i,r); row-scalars loaded once per row.
    float bv[4], sv[4], cvv[4];
#pragma unroll
    for (int j = 0; j < 4; ++j) {
        int col = n0 + wc + j * 16 + ml;
        bv[j] = bias[col];
        if (EPI == 3) { sv[j] = Svec[col]; cvv[j] = cvec[col]; }
    }
#pragma unroll
    for (int i = 0; i < 4; ++i) {
#pragma unroll
        for (int r = 0; r < 4; ++r) {
            int row = m0 + wr + i * 16 + q * 4 + r;
            if (EPI == 0) {
#pragma unroll
                for (int j = 0; j < 4; ++j) {
                    int col = n0 + wc + j * 16 + ml;
                    Cb[(size_t)row * N + col] = f2b(gelu_exact(acc[i][j][r] + bv[j]));
                }
            } else if (EPI == 2) {
                if (row < cnt_) {
                    int orow = rlist[row];
#pragma unroll
                    for (int j = 0; j < 4; ++j) {
                        int col = n0 + wc + j * 16 + ml;
                        Cb[(size_t)orow * N + col] = f2b(acc[i][j][r] + bv[j]);
                    }
                }
            } else {
                float rr = rs[row];
                float rm = rr * mu[row];
                float w = wm[row];
                const unsigned short* asrc = (idx[row] <= 1) ? adp : xn;
#pragma unroll
                for (int j = 0; j < 4; ++j) {
                    int col = n0 + wc + j * 16 + ml;
                    size_t off = (size_t)row * N + col;
                    float v2 = rr * acc[i][j][r] - rm * sv[j] + cvv[j] + bv[j];
                    float a = b2f(asrc[off]);
                    Cf[off] = v2 * w + a * (1.0f - w);
                }
            }
        }
    }
}

// ---------------------------------------------------------------------------
extern "C" void kernel_launch(void* const* d_in, const int* in_sizes, int n_in,
                              void* d_out, int out_size, void* d_ws, size_t ws_size,
                              hipStream_t stream) {
    const float* x       = (const float*)d_in[0];
    const float* wm      = (const float*)d_in[1];
    const int*   widx    = (const int*)d_in[2];
    const float* ln_in_g = (const float*)d_in[3];
    const float* ln_in_b = (const float*)d_in[4];
    const float* W1      = (const float*)d_in[5];
    const float* b1      = (const float*)d_in[6];
    const float* ln_h_g  = (const float*)d_in[7];
    const float* ln_h_b  = (const float*)d_in[8];
    const float* W2      = (const float*)d_in[9];
    const float* b2      = (const float*)d_in[10];
    const float* a256_w1 = (const float*)d_in[11];
    const float* a256_b1 = (const float*)d_in[12];
    const float* a256_w2 = (const float*)d_in[13];
    const float* a256_b2 = (const float*)d_in[14];
    const float* a512_w1 = (const float*)d_in[15];
    const float* a512_b1 = (const float*)d_in[16];
    const float* a512_w2 = (const float*)d_in[17];
    const float* a512_b2 = (const float*)d_in[18];
    float* out = (float*)d_out;

    const int T = 8192, H = 1024, F = 4096;

    unsigned short* ws0   = (unsigned short*)d_ws;
    unsigned short* xn    = ws0;                          // T*H          bf16
    unsigned short* h     = xn    + (size_t)T * H;        // T*F          bf16
    unsigned short* tc0   = h     + (size_t)T * F;        // (T+128)*256  bf16
    unsigned short* tc1   = tc0   + (size_t)(T + 128) * 256; // (T+128)*512
    unsigned short* adp   = tc1   + (size_t)(T + 128) * 512; // T*H
    unsigned short* W1T   = adp   + (size_t)T * H;        // F*H
    unsigned short* W2T   = W1T   + (size_t)H * F;        // H*F  (g-scaled)
    unsigned short* aw1T0 = W2T   + (size_t)F * H;        // 256*H
    unsigned short* aw1T1 = aw1T0 + (size_t)256 * H;      // 512*H
    unsigned short* aw2T0 = aw1T1 + (size_t)512 * H;      // H*256
    unsigned short* aw2T1 = aw2T0 + (size_t)H * 256;      // H*512
    float* fbase = (float*)(aw2T1 + (size_t)H * 512);
    float* Svec  = fbase;             // 1024
    float* cvec  = Svec + 1024;       // 1024
    float* muv   = cvec + 1024;       // 8192
    float* rsv   = muv + 8192;        // 8192
    int*   cnts  = (int*)(rsv + 8192);// 2
    int*   rl0   = cnts + 2;          // 8192
    int*   rl1   = rl0 + 8192;        // 8192
    // compacted xn copies: alias into h's space (h written only after adapters)
    unsigned short* xc0 = h;                              // (T+128)*H
    unsigned short* xc1 = h + (size_t)(T + 128) * H;      // (T+128)*H

    dim3 tb(32, 8);
    transpose_f32_bf16<<<dim3(F / 32,   H / 32), tb, 0, stream>>>(W1, W1T, H, F, nullptr);
    transpose_f32_bf16<<<dim3(H / 32,   F / 32), tb, 0, stream>>>(W2, W2T, F, H, ln_h_g);
    transpose_f32_bf16<<<dim3(256 / 32, H / 32), tb, 0, stream>>>(a256_w1, aw1T0, H, 256, nullptr);
    transpose_f32_bf16<<<dim3(512 / 32, H / 32), tb, 0, stream>>>(a512_w1, aw1T1, H, 512, nullptr);
    transpose_f32_bf16<<<dim3(H / 32, 256 / 32), tb, 0, stream>>>(a256_w2, aw2T0, 256, H, nullptr);
    transpose_f32_bf16<<<dim3(H / 32, 512 / 32), tb, 0, stream>>>(a512_w2, aw2T1, 512, H, nullptr);

    init_misc<<<4, 256, 0, stream>>>(Svec, cvec, cnts);
    colreduce_w2<<<dim3(4, 16), 256, 0, stream>>>(W2, ln_h_g, ln_h_b, Svec, cvec);
    build_lists<<<32, 256, 0, stream>>>(widx, cnts, rl0, rl1);

    // x (fp32) -> x_norm (bf16)
    ln1024<<<T, 256, 0, stream>>>(x, xn, ln_in_g, ln_in_b);

    // compact xn rows per adapter
    gather_rows<<<dim3(T, 2), 256, 0, stream>>>(xn, rl0, rl1, cnts, xc0, xc1);

    // adapter ups on compacted rows: tc = gelu(xc @ a_w1 + b)
    gemm_bt<0, true><<<dim3(2, 64), 256, 0, stream>>>(
        xc0, H, aw1T0, H, a256_b1, tc0, nullptr, 256, H,
        nullptr, cnts + 0, nullptr, nullptr, nullptr, nullptr, nullptr, nullptr, nullptr, nullptr);
    gemm_bt<0, true><<<dim3(4, 64), 256, 0, stream>>>(
        xc1, H, aw1T1, H, a512_b1, tc1, nullptr, 512, H,
        nullptr, cnts + 1, nullptr, nullptr, nullptr, nullptr, nullptr, nullptr, nullptr, nullptr);

    // adapter downs: adp[rl[r]] = tc @ a_w2 + b   (scatter epilogue)
    gemm_bt<2, true><<<dim3(8, 64), 256, 0, stream>>>(
        tc0, 256, aw2T0, 256, a256_b2, adp, nullptr, H, 256,
        rl0, cnts + 0, nullptr, nullptr, nullptr, nullptr, nullptr, nullptr, nullptr, nullptr);
    gemm_bt<2, true><<<dim3(8, 64), 256, 0, stream>>>(
        tc1, 512, aw2T1, 512, a512_b2, adp, nullptr, H, 512,
        rl1, cnts + 1, nullptr, nullptr, nullptr, nullptr, nullptr, nullptr, nullptr, nullptr);

    // base FFN up: h = gelu(xn @ W1 + b1)  (overwrites xc0/xc1 — no longer needed)
    gemm_bt<0, false><<<dim3(F / 128, T / 128), 256, 0, stream>>>(
        xn, H, W1T, H, b1, h, nullptr, F, H,
        nullptr, nullptr, nullptr, nullptr, nullptr, nullptr, nullptr, nullptr, nullptr, nullptr);

    // LN-h stats (LN itself folded into the final GEMM)
    row_stats<<<T, 256, 0, stream>>>(h, muv, rsv);

    // out = (LN(h) @ W2 + b2)*wm + adaptive*(1-wm), LN folded
    gemm_bt<3, false><<<dim3(H / 128, T / 128), 256, 0, stream>>>(
        h, F, W2T, F, b2, nullptr, out, H, F,
        nullptr, nullptr, widx, wm, adp, xn, muv, rsv, Svec, cvec);
}

// Round 7
// 470.732 us; speedup vs baseline: 1.2715x; 1.1119x over previous
//
#include <hip/hip_runtime.h>
#include <cstdint>
#include <cstddef>

typedef unsigned short u16x8 __attribute__((ext_vector_type(8)));
typedef unsigned short u16x4 __attribute__((ext_vector_type(4)));
typedef __bf16 bf16x8 __attribute__((ext_vector_type(8)));
typedef float f32x4 __attribute__((ext_vector_type(4)));

__device__ __forceinline__ float b2f(unsigned short u) {
    union { unsigned int i; float f; } v;
    v.i = ((unsigned int)u) << 16;
    return v.f;
}

__device__ __forceinline__ unsigned short f2b(float f) {
    union { float f; unsigned int i; } v;
    v.f = f;
    unsigned int x = v.i;
    unsigned int lsb = (x >> 16) & 1u;
    x += 0x7FFFu + lsb;           // round-to-nearest-even
    return (unsigned short)(x >> 16);
}

__device__ __forceinline__ float gelu_exact(float x) {
    return 0.5f * x * (1.0f + erff(x * 0.70710678118654752f));
}

// async 16B global -> LDS (DMA). LDS base wave-uniform; lane i -> base+16i.
__device__ __forceinline__ void ld_lds16(const unsigned short* g, unsigned short* l) {
    __builtin_amdgcn_global_load_lds(
        (const __attribute__((address_space(1))) void*)g,
        (__attribute__((address_space(3))) void*)l, 16, 0, 0);
}

// ---------------------------------------------------------------------------
// Transpose + cast (+ optional per-input-row scale): in R x C fp32 row-major,
// out C x R bf16 row-major. out[c,r] = scale[r]*in[r,c].
// ---------------------------------------------------------------------------
__global__ void transpose_f32_bf16(const float* __restrict__ in,
                                   unsigned short* __restrict__ out, int R, int C,
                                   const float* __restrict__ scale) {
    __shared__ float tile[32][33];
    int x = blockIdx.x * 32 + threadIdx.x;
    int y0 = blockIdx.y * 32;
    for (int k = 0; k < 32; k += 8) {
        float v = in[(size_t)(y0 + threadIdx.y + k) * C + x];
        if (scale) v *= scale[y0 + threadIdx.y + k];
        tile[threadIdx.y + k][threadIdx.x] = v;
    }
    __syncthreads();
    int ox = y0 + threadIdx.x;
    int oy = blockIdx.x * 32;
    for (int k = 0; k < 32; k += 8)
        out[(size_t)(oy + threadIdx.y + k) * R + ox] = f2b(tile[threadIdx.x][threadIdx.y + k]);
}

// zero S/cv and the two counters (ws is poisoned before every call)
__global__ void init_misc(float* __restrict__ S, float* __restrict__ cv,
                          int* __restrict__ cnt) {
    int t = blockIdx.x * 256 + threadIdx.x;
    if (t < 1024) { S[t] = 0.f; cv[t] = 0.f; }
    if (t < 2) cnt[t] = 0;
}

// S[c] = sum_f g[f]*W2[f,c];  cv[c] = sum_f b[f]*W2[f,c]   (W2 is F x H fp32)
// grid (4, 64): 64-row chunks -> 256 blocks (parallel enough to hide latency)
__global__ void colreduce_w2(const float* __restrict__ W2, const float* __restrict__ g,
                             const float* __restrict__ b, float* __restrict__ S,
                             float* __restrict__ cv) {
    int c = blockIdx.x * 256 + threadIdx.x;
    int f0 = blockIdx.y * 64;
    float s = 0.f, cc = 0.f;
    for (int f = f0; f < f0 + 64; ++f) {
        float w = W2[(size_t)f * 1024 + c];
        s = fmaf(g[f], w, s);
        cc = fmaf(b[f], w, cc);
    }
    atomicAdd(&S[c], s);
    atomicAdd(&cv[c], cc);
}

// Build compacted row lists per adapter; wave-aggregated atomics
// (1 atomicAdd per wave per list instead of 1 per matching lane).
__global__ void build_lists(const int* __restrict__ widx, int* __restrict__ cnt,
                            int* __restrict__ rl0, int* __restrict__ rl1) {
    int i = blockIdx.x * 256 + threadIdx.x;     // grid 32 -> 8192
    int lane = threadIdx.x & 63;
    int id = widx[i];
    unsigned long long m0 = __ballot(id == 0);
    unsigned long long m1 = __ballot(id == 1);
    unsigned long long lt = (lane == 0) ? 0ull : (~0ull >> (64 - lane));
    int b0 = 0, b1 = 0;
    if (lane == 0) {
        b0 = atomicAdd(&cnt[0], __popcll(m0));
        b1 = atomicAdd(&cnt[1], __popcll(m1));
    }
    b0 = __shfl(b0, 0, 64);
    b1 = __shfl(b1, 0, 64);
    if (id == 0)      rl0[b0 + __popcll(m0 & lt)] = i;
    else if (id == 1) rl1[b1 + __popcll(m1 & lt)] = i;
}

// xc[r,:] = xn[rl[r],:] for r < cnt. grid (128, 2), grid-stride over rows.
__global__ __launch_bounds__(256) void gather_rows(
    const unsigned short* __restrict__ xn,
    const int* __restrict__ rl0, const int* __restrict__ rl1,
    const int* __restrict__ cnt,
    unsigned short* __restrict__ xc0, unsigned short* __restrict__ xc1) {
    const int list = blockIdx.y;
    const int n = cnt[list];
    const int* rl = list ? rl1 : rl0;
    unsigned short* dst = list ? xc1 : xc0;
    for (int r = blockIdx.x; r < n; r += gridDim.x) {
        int src = rl[r];
        ((u16x4*)(dst + (size_t)r * 1024))[threadIdx.x] =
            ((const u16x4*)(xn + (size_t)src * 1024))[threadIdx.x];
    }
}

// ---------------------------------------------------------------------------
// LayerNorm of x (fp32, 1024 cols) -> bf16, vectorized float4.
// ---------------------------------------------------------------------------
__global__ __launch_bounds__(256) void ln1024(const float* __restrict__ x,
                                              unsigned short* __restrict__ xn,
                                              const float* __restrict__ g,
                                              const float* __restrict__ b) {
    const int row = blockIdx.x, t = threadIdx.x;
    const float4 v = ((const float4*)(x + (size_t)row * 1024))[t];
    float s = v.x + v.y + v.z + v.w;
    float s2 = v.x * v.x + v.y * v.y + v.z * v.z + v.w * v.w;
#pragma unroll
    for (int o = 32; o > 0; o >>= 1) {
        s  += __shfl_down(s, o, 64);
        s2 += __shfl_down(s2, o, 64);
    }
    __shared__ float red[8];
    int lane = t & 63, w = t >> 6;
    if (lane == 0) { red[w] = s; red[4 + w] = s2; }
    __syncthreads();
    if (t == 0) {
        red[0] = red[0] + red[1] + red[2] + red[3];
        red[4] = red[4] + red[5] + red[6] + red[7];
    }
    __syncthreads();
    float mu = red[0] * (1.0f / 1024.0f);
    float var = red[4] * (1.0f / 1024.0f) - mu * mu;
    float rs = rsqrtf(var + 1e-5f);
    float4 gg = ((const float4*)g)[t];
    float4 bb = ((const float4*)b)[t];
    u16x4 o;
    o[0] = f2b((v.x - mu) * rs * gg.x + bb.x);
    o[1] = f2b((v.y - mu) * rs * gg.y + bb.y);
    o[2] = f2b((v.z - mu) * rs * gg.z + bb.z);
    o[3] = f2b((v.w - mu) * rs * gg.w + bb.w);
    ((u16x4*)(xn + (size_t)row * 1024))[t] = o;
}

// Per-row mean / rsqrt(var) of h (bf16, 4096 cols), vectorized u16x8.
__global__ __launch_bounds__(256) void row_stats(const unsigned short* __restrict__ h,
                                                 float* __restrict__ mu,
                                                 float* __restrict__ rs) {
    const int row = blockIdx.x, t = threadIdx.x;
    const u16x8* hv = (const u16x8*)(h + (size_t)row * 4096);
    float s = 0.f, s2 = 0.f;
#pragma unroll
    for (int i = 0; i < 2; ++i) {
        u16x8 v = hv[t + i * 256];
#pragma unroll
        for (int e = 0; e < 8; ++e) { float f = b2f(v[e]); s += f; s2 += f * f; }
    }
#pragma unroll
    for (int o = 32; o > 0; o >>= 1) {
        s  += __shfl_down(s, o, 64);
        s2 += __shfl_down(s2, o, 64);
    }
    __shared__ float red[8];
    int lane = t & 63, w = t >> 6;
    if (lane == 0) { red[w] = s; red[4 + w] = s2; }
    __syncthreads();
    if (t == 0) {
        float S  = red[0] + red[1] + red[2] + red[3];
        float S2 = red[4] + red[5] + red[6] + red[7];
        float m = S * (1.0f / 4096.0f);
        float var = S2 * (1.0f / 4096.0f) - m * m;
        mu[row] = m;
        rs[row] = rsqrtf(var + 1e-5f);
    }
}

// ---------------------------------------------------------------------------
// GEMM: A[M x K] * BT[N x K]^T (+ epilogue). A,BT bf16; fp32 acc.
// Tile 128x128x32; 256 threads = 4 waves, each 64x64. Double-buffered LDS,
// one barrier per K-iter.
// SWIZ: 1D grid, XCD-aware: blk&7 selects XCD-owned M-chunk, n innermost ->
//       A-tiles stay L2-resident within an XCD (cuts h re-fetch 8x).
// GATED: wave-uniform early exit when the M-block is beyond *cnt.
// EPI 0: store bf16 gelu(val+bias)                      (ups; A may be compact)
// EPI 2: scatter bf16 (val+bias) -> Cb[rlist[row]]       (adapter downs)
// EPI 3: LN-fold + adaptive combine, fp32 out            (final GEMM)
// ---------------------------------------------------------------------------
template <int EPI, bool GATED, bool SWIZ>
__global__ __launch_bounds__(256, 4) void gemm_bt(
    const unsigned short* __restrict__ A, int lda,
    const unsigned short* __restrict__ BT, int ldb,
    const float* __restrict__ bias,
    unsigned short* __restrict__ Cb, float* __restrict__ Cf, int N, int K,
    int nbn,
    const int* __restrict__ rlist, const int* __restrict__ cnt,
    const int* __restrict__ idx, const float* __restrict__ wm,
    const unsigned short* __restrict__ adp, const unsigned short* __restrict__ xn,
    const float* __restrict__ mu, const float* __restrict__ rs,
    const float* __restrict__ Svec, const float* __restrict__ cvec) {
    __shared__ __align__(16) unsigned short As[2][128 * 32];
    __shared__ __align__(16) unsigned short Bs[2][128 * 32];

    int m0, n0;
    if (SWIZ) {
        int blk = blockIdx.x;
        int pos = blk >> 3;
        int per = (gridDim.x >> 3) / nbn;       // m-blocks per XCD
        int mb = (blk & 7) * per + pos / nbn;   // n innermost
        m0 = mb * 128;
        n0 = (pos % nbn) * 128;
    } else {
        m0 = blockIdx.y * 128;
        n0 = blockIdx.x * 128;
    }

    int cnt_ = 0;
    if (GATED) {
        cnt_ = *cnt;
        if (m0 >= cnt_) return;          // wave-uniform early exit
    }

    const int t = threadIdx.x;
    const int lane = t & 63;
    const int wid = t >> 6;

    // staging: lane i covers LDS rel-row i/4, chunk i%4 (XOR row-swizzled src)
    const int srow = lane >> 2;
    const int scol = ((lane & 3) ^ (srow & 3)) << 3;

    const int wr = (wid >> 1) << 6;
    const int wc = (wid & 1) << 6;
    const int ml = lane & 15;
    const int q = lane >> 4;
    const int qsw = ((q ^ (ml & 3)) << 3);

    f32x4 acc[4][4];
#pragma unroll
    for (int i = 0; i < 4; ++i)
#pragma unroll
        for (int j = 0; j < 4; ++j)
#pragma unroll
            for (int r = 0; r < 4; ++r) acc[i][j][r] = 0.0f;

    const int nk = K >> 5;

#define STAGE(KT, BUF)                                                          \
    {                                                                           \
        _Pragma("unroll")                                                       \
        for (int hh = 0; hh < 2; ++hh) {                                        \
            int rbase = wid * 32 + hh * 16;                                     \
            int row = rbase + srow;                                             \
            ld_lds16(A  + (size_t)(m0 + row) * lda + (KT) * 32 + scol,          \
                     &As[BUF][rbase * 32]);                                     \
            ld_lds16(BT + (size_t)(n0 + row) * ldb + (KT) * 32 + scol,          \
                     &Bs[BUF][rbase * 32]);                                     \
        }                                                                       \
    }

    STAGE(0, 0);
    for (int kt = 0; kt < nk; ++kt) {
        const int cur = kt & 1;
        __syncthreads();                 // drains DMA(kt), in flight since kt-1
        if (kt + 1 < nk) STAGE(kt + 1, cur ^ 1);

        bf16x8 af[4], bf[4];
#pragma unroll
        for (int i = 0; i < 4; ++i)
            af[i] = *(const bf16x8*)(&As[cur][(wr + i * 16 + ml) * 32 + qsw]);
#pragma unroll
        for (int j = 0; j < 4; ++j)
            bf[j] = *(const bf16x8*)(&Bs[cur][(wc + j * 16 + ml) * 32 + qsw]);
#pragma unroll
        for (int i = 0; i < 4; ++i)
#pragma unroll
            for (int j = 0; j < 4; ++j)
                acc[i][j] = __builtin_amdgcn_mfma_f32_16x16x32_bf16(af[i], bf[j], acc[i][j], 0, 0, 0);
    }
#undef STAGE

    // Epilogue. C/D layout: col = lane&15, row = quad*4 + reg [m89/m91].
    float bv[4], sv[4], cvv[4];
#pragma unroll
    for (int j = 0; j < 4; ++j) {
        int col = n0 + wc + j * 16 + ml;
        bv[j] = bias[col];
        if (EPI == 3) { sv[j] = Svec[col]; cvv[j] = cvec[col]; }
    }
#pragma unroll
    for (int i = 0; i < 4; ++i) {
#pragma unroll
        for (int r = 0; r < 4; ++r) {
            int row = m0 + wr + i * 16 + q * 4 + r;
            if (EPI == 0) {
#pragma unroll
                for (int j = 0; j < 4; ++j) {
                    int col = n0 + wc + j * 16 + ml;
                    Cb[(size_t)row * N + col] = f2b(gelu_exact(acc[i][j][r] + bv[j]));
                }
            } else if (EPI == 2) {
                if (row < cnt_) {
                    int orow = rlist[row];
#pragma unroll
                    for (int j = 0; j < 4; ++j) {
                        int col = n0 + wc + j * 16 + ml;
                        Cb[(size_t)orow * N + col] = f2b(acc[i][j][r] + bv[j]);
                    }
                }
            } else {
                float rr = rs[row];
                float rm = rr * mu[row];
                float w = wm[row];
                const unsigned short* asrc = (idx[row] <= 1) ? adp : xn;
#pragma unroll
                for (int j = 0; j < 4; ++j) {
                    int col = n0 + wc + j * 16 + ml;
                    size_t off = (size_t)row * N + col;
                    float v2 = rr * acc[i][j][r] - rm * sv[j] + cvv[j] + bv[j];
                    float a = b2f(asrc[off]);
                    Cf[off] = v2 * w + a * (1.0f - w);
                }
            }
        }
    }
}

// ---------------------------------------------------------------------------
extern "C" void kernel_launch(void* const* d_in, const int* in_sizes, int n_in,
                              void* d_out, int out_size, void* d_ws, size_t ws_size,
                              hipStream_t stream) {
    const float* x       = (const float*)d_in[0];
    const float* wm      = (const float*)d_in[1];
    const int*   widx    = (const int*)d_in[2];
    const float* ln_in_g = (const float*)d_in[3];
    const float* ln_in_b = (const float*)d_in[4];
    const float* W1      = (const float*)d_in[5];
    const float* b1      = (const float*)d_in[6];
    const float* ln_h_g  = (const float*)d_in[7];
    const float* ln_h_b  = (const float*)d_in[8];
    const float* W2      = (const float*)d_in[9];
    const float* b2      = (const float*)d_in[10];
    const float* a256_w1 = (const float*)d_in[11];
    const float* a256_b1 = (const float*)d_in[12];
    const float* a256_w2 = (const float*)d_in[13];
    const float* a256_b2 = (const float*)d_in[14];
    const float* a512_w1 = (const float*)d_in[15];
    const float* a512_b1 = (const float*)d_in[16];
    const float* a512_w2 = (const float*)d_in[17];
    const float* a512_b2 = (const float*)d_in[18];
    float* out = (float*)d_out;

    const int T = 8192, H = 1024, F = 4096;

    unsigned short* ws0   = (unsigned short*)d_ws;
    unsigned short* xn    = ws0;                          // T*H          bf16
    unsigned short* h     = xn    + (size_t)T * H;        // T*F          bf16
    unsigned short* tc0   = h     + (size_t)T * F;        // (T+128)*256  bf16
    unsigned short* tc1   = tc0   + (size_t)(T + 128) * 256; // (T+128)*512
    unsigned short* adp   = tc1   + (size_t)(T + 128) * 512; // T*H
    unsigned short* W1T   = adp   + (size_t)T * H;        // F*H
    unsigned short* W2T   = W1T   + (size_t)H * F;        // H*F  (g-scaled)
    unsigned short* aw1T0 = W2T   + (size_t)F * H;        // 256*H
    unsigned short* aw1T1 = aw1T0 + (size_t)256 * H;      // 512*H
    unsigned short* aw2T0 = aw1T1 + (size_t)512 * H;      // H*256
    unsigned short* aw2T1 = aw2T0 + (size_t)H * 256;      // H*512
    float* fbase = (float*)(aw2T1 + (size_t)H * 512);
    float* Svec  = fbase;             // 1024
    float* cvec  = Svec + 1024;       // 1024
    float* muv   = cvec + 1024;       // 8192
    float* rsv   = muv + 8192;        // 8192
    int*   cnts  = (int*)(rsv + 8192);// 2
    int*   rl0   = cnts + 2;          // 8192
    int*   rl1   = rl0 + 8192;        // 8192
    // compacted xn copies: alias into h's space (h written only after adapters)
    unsigned short* xc0 = h;                              // (T+128)*H
    unsigned short* xc1 = h + (size_t)(T + 128) * H;      // (T+128)*H

    dim3 tb(32, 8);
    transpose_f32_bf16<<<dim3(F / 32,   H / 32), tb, 0, stream>>>(W1, W1T, H, F, nullptr);
    transpose_f32_bf16<<<dim3(H / 32,   F / 32), tb, 0, stream>>>(W2, W2T, F, H, ln_h_g);
    transpose_f32_bf16<<<dim3(256 / 32, H / 32), tb, 0, stream>>>(a256_w1, aw1T0, H, 256, nullptr);
    transpose_f32_bf16<<<dim3(512 / 32, H / 32), tb, 0, stream>>>(a512_w1, aw1T1, H, 512, nullptr);
    transpose_f32_bf16<<<dim3(H / 32, 256 / 32), tb, 0, stream>>>(a256_w2, aw2T0, 256, H, nullptr);
    transpose_f32_bf16<<<dim3(H / 32, 512 / 32), tb, 0, stream>>>(a512_w2, aw2T1, 512, H, nullptr);

    init_misc<<<4, 256, 0, stream>>>(Svec, cvec, cnts);
    colreduce_w2<<<dim3(4, 64), 256, 0, stream>>>(W2, ln_h_g, ln_h_b, Svec, cvec);
    build_lists<<<32, 256, 0, stream>>>(widx, cnts, rl0, rl1);

    // x (fp32) -> x_norm (bf16)
    ln1024<<<T, 256, 0, stream>>>(x, xn, ln_in_g, ln_in_b);

    // compact xn rows per adapter
    gather_rows<<<dim3(128, 2), 256, 0, stream>>>(xn, rl0, rl1, cnts, xc0, xc1);

    // adapter ups on compacted rows: tc = gelu(xc @ a_w1 + b)
    gemm_bt<0, true, false><<<dim3(2, 64), 256, 0, stream>>>(
        xc0, H, aw1T0, H, a256_b1, tc0, nullptr, 256, H, 0,
        nullptr, cnts + 0, nullptr, nullptr, nullptr, nullptr, nullptr, nullptr, nullptr, nullptr);
    gemm_bt<0, true, false><<<dim3(4, 64), 256, 0, stream>>>(
        xc1, H, aw1T1, H, a512_b1, tc1, nullptr, 512, H, 0,
        nullptr, cnts + 1, nullptr, nullptr, nullptr, nullptr, nullptr, nullptr, nullptr, nullptr);

    // adapter downs: adp[rl[r]] = tc @ a_w2 + b   (scatter epilogue)
    gemm_bt<2, true, false><<<dim3(8, 64), 256, 0, stream>>>(
        tc0, 256, aw2T0, 256, a256_b2, adp, nullptr, H, 256, 0,
        rl0, cnts + 0, nullptr, nullptr, nullptr, nullptr, nullptr, nullptr, nullptr, nullptr);
    gemm_bt<2, true, false><<<dim3(8, 64), 256, 0, stream>>>(
        tc1, 512, aw2T1, 512, a512_b2, adp, nullptr, H, 512, 0,
        rl1, cnts + 1, nullptr, nullptr, nullptr, nullptr, nullptr, nullptr, nullptr, nullptr);

    // base FFN up: h = gelu(xn @ W1 + b1)   (XCD-swizzled 1D grid: nbm=64, nbn=32)
    gemm_bt<0, false, true><<<2048, 256, 0, stream>>>(
        xn, H, W1T, H, b1, h, nullptr, F, H, 32,
        nullptr, nullptr, nullptr, nullptr, nullptr, nullptr, nullptr, nullptr, nullptr, nullptr);

    // LN-h stats (LN itself folded into the final GEMM)
    row_stats<<<T, 256, 0, stream>>>(h, muv, rsv);

    // out = (LN(h) @ W2 + b2)*wm + adaptive*(1-wm)   (XCD-swizzled: nbm=64, nbn=8)
    gemm_bt<3, false, true><<<512, 256, 0, stream>>>(
        h, F, W2T, F, b2, nullptr, out, H, F, 8,
        nullptr, nullptr, widx, wm, adp, xn, muv, rsv, Svec, cvec);
}